// Round 3
// baseline (214.502 us; speedup 1.0000x reference)
//
#include <hip/hip_runtime.h>

// RoiAlign fused: level-select + crop_and_resize(7x7 bilinear, extrap 0)
// feat0: [B,256,256,256] f32 NHWC ; feat1: [B,128,128,256] f32 ; rois: [B,R,5]
// out: [B,R,7,7,256] f32
//
// Mapping: ONE BLOCK PER BOX (256 thr = 4 waves). Each wave handles pool
// positions p = wave, wave+4, ... so all 196 bilinear taps of a box are
// served by the same CU's L1/L2. Lane -> 4 channels via float4; all global
// accesses 16B/lane coalesced.
//
// NOTE: plain (cached) stores only. __builtin_nontemporal_store here caused
// post-timing divergence: the harness re-poisons d_out through the cached
// path (dirty L2 lines); an NT store that bypasses L2 gets overwritten when
// the stale dirty poison line is later evicted. Do not reintroduce.

#define POOL 7
#define NCH 256

typedef float v4f __attribute__((ext_vector_type(4)));

__global__ __launch_bounds__(256) void roialign_kernel(
    const float* __restrict__ feat0,
    const float* __restrict__ feat1,
    const float* __restrict__ rois,
    float* __restrict__ out,
    int NB, int R) // NB = B*R
{
    int n = blockIdx.x;
    if (n >= NB) return;
    int lane = threadIdx.x & 63;  // channel group: channels [4*lane .. 4*lane+3]
    int wave = threadIdx.x >> 6;  // 0..3

    const float* roi = rois + (size_t)n * 5;
    float y1 = roi[0], x1 = roi[1], y2 = roi[2], x2 = roi[3];

    // level select on RAW box coords, matching ref
    bool lvl = (y2 - y1 > 48.0f) || (x2 - x1 > 48.0f);
    const float* feat = lvl ? feat1 : feat0;
    int H = lvl ? 128 : 256;
    int W = H;
    int b = n / R;

    const float inv_img = 1.0f / 1024.0f;
    float y1n = y1 * inv_img, y2n = y2 * inv_img;
    float x1n = x1 * inv_img, x2n = x2 * inv_img;
    float Hm1 = (float)(H - 1), Wm1 = (float)(W - 1);
    float dy = y2n - y1n, dx = x2n - x1n;

    size_t plane = (size_t)b * H * W;
    int coff = lane * 4;
    float* outbase = out + (size_t)n * 49 * NCH + coff;

    for (int p = wave; p < 49; p += 4) {
        int i = p / POOL;           // const divisor -> mul+shift
        int j = p - i * POOL;

        // same float op order as reference
        float ys = (y1n + ((float)i / 6.0f) * dy) * Hm1;
        float xs = (x1n + ((float)j / 6.0f) * dx) * Wm1;

        float y0f = floorf(ys), x0f = floorf(xs);
        float wy = ys - y0f;
        float wx = xs - x0f;

        int y0 = (int)fminf(fmaxf(y0f,        0.0f), Hm1);
        int yp = (int)fminf(fmaxf(y0f + 1.0f, 0.0f), Hm1);
        int x0 = (int)fminf(fmaxf(x0f,        0.0f), Wm1);
        int xp = (int)fminf(fmaxf(x0f + 1.0f, 0.0f), Wm1);

        bool valid = (ys >= 0.0f) && (ys <= Hm1) && (xs >= 0.0f) && (xs <= Wm1);

        size_t r0 = (plane + (size_t)y0 * W) * NCH;
        size_t r1 = (plane + (size_t)yp * W) * NCH;

        v4f v00 = *(const v4f*)(feat + r0 + (size_t)x0 * NCH + coff);
        v4f v01 = *(const v4f*)(feat + r0 + (size_t)xp * NCH + coff);
        v4f v10 = *(const v4f*)(feat + r1 + (size_t)x0 * NCH + coff);
        v4f v11 = *(const v4f*)(feat + r1 + (size_t)xp * NCH + coff);

        float wx1 = 1.0f - wx, wy1 = 1.0f - wy;
        v4f top = v00 * wx1 + v01 * wx;
        v4f bot = v10 * wx1 + v11 * wx;
        v4f o   = top * wy1 + bot * wy;
        if (!valid) o = (v4f)0.0f;

        *(v4f*)(outbase + (size_t)p * NCH) = o;
    }
}

extern "C" void kernel_launch(void* const* d_in, const int* in_sizes, int n_in,
                              void* d_out, int out_size, void* d_ws, size_t ws_size,
                              hipStream_t stream) {
    const float* feat0 = (const float*)d_in[0];
    const float* feat1 = (const float*)d_in[1];
    const float* rois  = (const float*)d_in[2];
    float* out = (float*)d_out;

    int B  = in_sizes[0] / (256 * 256 * 256); // feat0 = [B,256,256,256]
    int NB = in_sizes[2] / 5;                 // rois  = [B,R,5] -> B*R boxes
    int R  = NB / B;

    roialign_kernel<<<NB, 256, 0, stream>>>(feat0, feat1, rois, out, NB, R);
}

// Round 4
// 208.930 us; speedup vs baseline: 1.0267x; 1.0267x over previous
//
#include <hip/hip_runtime.h>

// RoiAlign fused: level-select + crop_and_resize(7x7 bilinear, extrap 0)
// feat0: [B,256,256,256] f32 NHWC ; feat1: [B,128,128,256] f32 ; rois: [B,R,5]
// out: [B,R,7,7,256] f32
//
// Mapping: ONE WAVE PER PAIR of pool positions (25 waves/box; wave q handles
// p=2q,2q+1; q==24 handles p=48 alone). Lane -> 4 channels via float4.
// Rationale (R1 vs R3 A/B): gather-latency bound; want max waves in flight
// AND max loads-in-flight per wave. This doubles per-wave MLP (8 outstanding
// 16B/lane loads) vs R1 while keeping a 6400-block one-shot grid.
//
// NOTE: plain (cached) stores only. __builtin_nontemporal_store caused
// post-timing divergence (harness re-poisons d_out through the cached path;
// NT-stored lines get clobbered by later eviction of stale dirty poison
// lines). Do not reintroduce.

#define POOL 7
#define NCH 256

typedef float v4f __attribute__((ext_vector_type(4)));

__global__ __launch_bounds__(256) void roialign_kernel(
    const float* __restrict__ feat0,
    const float* __restrict__ feat1,
    const float* __restrict__ rois,
    float* __restrict__ out,
    int NB, int R) // NB = B*R
{
    int t = blockIdx.x * blockDim.x + threadIdx.x;
    int lane = t & 63;          // channel group: channels [4*lane .. 4*lane+3]
    int wid  = t >> 6;          // n*25 + q
    int n    = wid / 25;
    if (n >= NB) return;
    int q    = wid - n * 25;
    int p0   = q * 2;
    bool has2 = (q < 24);
    int p1   = has2 ? p0 + 1 : p0;   // q==24: duplicate p0, store skipped

    const float* roi = rois + (size_t)n * 5;
    float y1 = roi[0], x1 = roi[1], y2 = roi[2], x2 = roi[3];

    // level select on RAW box coords, matching ref
    bool lvl = (y2 - y1 > 48.0f) || (x2 - x1 > 48.0f);
    const float* feat = lvl ? feat1 : feat0;
    int H = lvl ? 128 : 256;
    int W = H;
    int b = n / R;

    const float inv_img = 1.0f / 1024.0f;
    float y1n = y1 * inv_img, y2n = y2 * inv_img;
    float x1n = x1 * inv_img, x2n = x2 * inv_img;
    float Hm1 = (float)(H - 1), Wm1 = (float)(W - 1);
    float dy = y2n - y1n, dx = x2n - x1n;

    size_t plane = (size_t)b * H * W;
    int coff = lane * 4;
    float* outbase = out + (size_t)n * 49 * NCH + coff;

    // ---- position 0 ----
    int i0 = p0 / POOL, j0 = p0 - i0 * POOL;
    float ys0 = (y1n + ((float)i0 / 6.0f) * dy) * Hm1;
    float xs0 = (x1n + ((float)j0 / 6.0f) * dx) * Wm1;
    float y0f0 = floorf(ys0), x0f0 = floorf(xs0);
    float wy0 = ys0 - y0f0, wx0 = xs0 - x0f0;
    int ya0 = (int)fminf(fmaxf(y0f0,        0.0f), Hm1);
    int yb0 = (int)fminf(fmaxf(y0f0 + 1.0f, 0.0f), Hm1);
    int xa0 = (int)fminf(fmaxf(x0f0,        0.0f), Wm1);
    int xb0 = (int)fminf(fmaxf(x0f0 + 1.0f, 0.0f), Wm1);
    bool valid0 = (ys0 >= 0.0f) && (ys0 <= Hm1) && (xs0 >= 0.0f) && (xs0 <= Wm1);
    size_t r00 = (plane + (size_t)ya0 * W) * NCH;
    size_t r10 = (plane + (size_t)yb0 * W) * NCH;

    // ---- position 1 ----
    int i1 = p1 / POOL, j1 = p1 - i1 * POOL;
    float ys1 = (y1n + ((float)i1 / 6.0f) * dy) * Hm1;
    float xs1 = (x1n + ((float)j1 / 6.0f) * dx) * Wm1;
    float y0f1 = floorf(ys1), x0f1 = floorf(xs1);
    float wy1w = ys1 - y0f1, wx1w = xs1 - x0f1;
    int ya1 = (int)fminf(fmaxf(y0f1,        0.0f), Hm1);
    int yb1 = (int)fminf(fmaxf(y0f1 + 1.0f, 0.0f), Hm1);
    int xa1 = (int)fminf(fmaxf(x0f1,        0.0f), Wm1);
    int xb1 = (int)fminf(fmaxf(x0f1 + 1.0f, 0.0f), Wm1);
    bool valid1 = (ys1 >= 0.0f) && (ys1 <= Hm1) && (xs1 >= 0.0f) && (xs1 <= Wm1);
    size_t r01 = (plane + (size_t)ya1 * W) * NCH;
    size_t r11 = (plane + (size_t)yb1 * W) * NCH;

    // ---- 8 independent loads (max loads-in-flight before first use) ----
    v4f a00 = *(const v4f*)(feat + r00 + (size_t)xa0 * NCH + coff);
    v4f a01 = *(const v4f*)(feat + r00 + (size_t)xb0 * NCH + coff);
    v4f a10 = *(const v4f*)(feat + r10 + (size_t)xa0 * NCH + coff);
    v4f a11 = *(const v4f*)(feat + r10 + (size_t)xb0 * NCH + coff);
    v4f b00 = *(const v4f*)(feat + r01 + (size_t)xa1 * NCH + coff);
    v4f b01 = *(const v4f*)(feat + r01 + (size_t)xb1 * NCH + coff);
    v4f b10 = *(const v4f*)(feat + r11 + (size_t)xa1 * NCH + coff);
    v4f b11 = *(const v4f*)(feat + r11 + (size_t)xb1 * NCH + coff);

    {
        float wxc = 1.0f - wx0, wyc = 1.0f - wy0;
        v4f top = a00 * wxc + a01 * wx0;
        v4f bot = a10 * wxc + a11 * wx0;
        v4f o   = top * wyc + bot * wy0;
        if (!valid0) o = (v4f)0.0f;
        *(v4f*)(outbase + (size_t)p0 * NCH) = o;
    }
    if (has2) {
        float wxc = 1.0f - wx1w, wyc = 1.0f - wy1w;
        v4f top = b00 * wxc + b01 * wx1w;
        v4f bot = b10 * wxc + b11 * wx1w;
        v4f o   = top * wyc + bot * wy1w;
        if (!valid1) o = (v4f)0.0f;
        *(v4f*)(outbase + (size_t)p1 * NCH) = o;
    }
}

extern "C" void kernel_launch(void* const* d_in, const int* in_sizes, int n_in,
                              void* d_out, int out_size, void* d_ws, size_t ws_size,
                              hipStream_t stream) {
    const float* feat0 = (const float*)d_in[0];
    const float* feat1 = (const float*)d_in[1];
    const float* rois  = (const float*)d_in[2];
    float* out = (float*)d_out;

    int B  = in_sizes[0] / (256 * 256 * 256); // feat0 = [B,256,256,256]
    int NB = in_sizes[2] / 5;                 // rois  = [B,R,5] -> B*R boxes
    int R  = NB / B;

    // 25 waves per box (2 pool positions per wave), 64 lanes each
    long long threads = (long long)NB * 25 * 64;
    int block = 256;
    int grid = (int)((threads + block - 1) / block);
    roialign_kernel<<<grid, block, 0, stream>>>(feat0, feat1, rois, out, NB, R);
}